// Round 3
// baseline (474.756 us; speedup 1.0000x reference)
//
#include <hip/hip_runtime.h>
#include <math.h>

// MultiHeadAdapter: B=8,S=4096,H=8,D=128,K=32, fp32 in/out
#define NB 8
#define NS 4096
#define NH 8
#define ND 128
#define NK 32
#define NT (NB*NS)          // 32768 tokens
#define HD (NH*ND)          // 1024

#define LN_EPS_F 1e-5f
#define BN_EPS_F 1e-5f
#define ADAPTER_SCALE 0.1f

#define THREADS 256
#define NWAVES 4
#define BPH 256                       // blocks per head
#define NBLK (NH*BPH)                 // 2048 blocks
#define TPW 2                         // 16-token tiles per wave

typedef short short8 __attribute__((ext_vector_type(8)));
typedef float f32x4 __attribute__((ext_vector_type(4)));

__device__ inline unsigned short f2bf(float f) {
    union { float f; unsigned u; } v; v.f = f;
    unsigned r = v.u + 0x7fffu + ((v.u >> 16) & 1u);   // RNE
    return (unsigned short)(r >> 16);
}

__global__ void zero_kernel(float* p, int n) {
    int i = blockIdx.x * blockDim.x + threadIdx.x;
    if (i < n) p[i] = 0.0f;
}

// MODE 0: compute h (pre-BN), accumulate per-(h,d) sum/sumsq.
// MODE 1: recompute h, apply out = a*h + c + x.
template <int MODE>
__global__ __launch_bounds__(THREADS, 4)
void adapter_mfma(const float* __restrict__ x,
                  const float* __restrict__ ln_g, const float* __restrict__ ln_b,
                  const float* __restrict__ w_down, const float* __restrict__ b_down,
                  const float* __restrict__ w_up, const float* __restrict__ b_up,
                  float* __restrict__ gsum, float* __restrict__ gssq,
                  const float* __restrict__ avec, const float* __restrict__ cvec,
                  float* __restrict__ out)
{
    __shared__ __align__(16) unsigned short s_gl[NWAVES][16*40];  // GELU out bf16 (padded rows)
    __shared__ __align__(16) float s_lng[ND];
    __shared__ __align__(16) float s_lnb[ND];
    __shared__ float s_stats[2][ND];

    const int h    = blockIdx.x & 7;
    const int bidx = blockIdx.x >> 3;      // 0..255
    const int tid  = threadIdx.x;
    const int wave = tid >> 6;
    const int lane = tid & 63;
    const int lg   = lane >> 4;            // 0..3
    const int lc   = lane & 15;            // 0..15

    if (tid < ND) { s_lng[tid] = ln_g[h*ND + tid]; s_lnb[tid] = ln_b[h*ND + tid]; }
    else if (MODE == 0 && tid < 2*ND) { s_stats[0][tid - ND] = 0.f; s_stats[1][tid - ND] = 0.f; }
    __syncthreads();

    // ---- weights -> MFMA B-fragments in registers (once per block) ----
    // B-frag: lane l holds B[k = 8*(l>>4)+i][n = l&15], i=0..7
    short8 wd[4][2];     // down: K=128 (4 steps of 32) x N=32 (2 tiles of 16)
    #pragma unroll
    for (int s = 0; s < 4; ++s)
        #pragma unroll
        for (int nt = 0; nt < 2; ++nt)
            #pragma unroll
            for (int i = 0; i < 8; ++i)
                wd[s][nt][i] = (short)f2bf(w_down[h*ND*NK + (32*s + 8*lg + i)*NK + 16*nt + lc]);
    short8 wu[8];        // up: K=32 x N=128 (8 tiles of 16)
    #pragma unroll
    for (int nt = 0; nt < 8; ++nt)
        #pragma unroll
        for (int i = 0; i < 8; ++i)
            wu[nt][i] = (short)f2bf(w_up[h*NK*ND + (8*lg + i)*ND + 16*nt + lc]);

    float bdreg[2];
    #pragma unroll
    for (int nt = 0; nt < 2; ++nt) bdreg[nt] = b_down[h*NK + 16*nt + lc];
    float bupreg[8];
    #pragma unroll
    for (int nt = 0; nt < 8; ++nt) bupreg[nt] = b_up[h*ND + 16*nt + lc];

    float areg[8], cfold[8];
    if constexpr (MODE == 1) {
        #pragma unroll
        for (int nt = 0; nt < 8; ++nt) {
            areg[nt]  = avec[h*ND + 16*nt + lc];
            cfold[nt] = fmaf(areg[nt], bupreg[nt], cvec[h*ND + 16*nt + lc]); // fold b_up
        }
    }

    float sumacc[8], ssqacc[8];
    #pragma unroll
    for (int nt = 0; nt < 8; ++nt) { sumacc[nt] = 0.f; ssqacc[nt] = 0.f; }

    for (int it = 0; it < TPW; ++it) {
        const int tbase = bidx*128 + (wave + NWAVES*it)*16;

        // ---- load this lane's A-fragment slice of x directly (token lc, d=32s+8lg+..) ----
        const float* xrow = x + (size_t)(tbase + lc)*HD + h*ND + 8*lg;
        f32x4 xv[4][2];
        #pragma unroll
        for (int s = 0; s < 4; ++s) {
            xv[s][0] = *(const f32x4*)(xrow + 32*s);
            xv[s][1] = *(const f32x4*)(xrow + 32*s + 4);
        }

        // ---- LayerNorm: per-lane partial sums + 2-level cross-lane reduce ----
        float s1 = 0.f, s2 = 0.f;
        #pragma unroll
        for (int s = 0; s < 4; ++s)
            #pragma unroll
            for (int hf = 0; hf < 2; ++hf)
                #pragma unroll
                for (int j = 0; j < 4; ++j) {
                    const float v = xv[s][hf][j];
                    s1 += v;
                    s2 = fmaf(v, v, s2);
                }
        s1 += __shfl_xor(s1, 16);  s2 += __shfl_xor(s2, 16);
        s1 += __shfl_xor(s1, 32);  s2 += __shfl_xor(s2, 32);
        const float mu   = s1 * (1.0f/ND);
        const float rstd = rsqrtf(s2*(1.0f/ND) - mu*mu + LN_EPS_F);

        // ---- normalize + affine + pack to bf16 A-fragments in-register ----
        short8 ax[4];
        #pragma unroll
        for (int s = 0; s < 4; ++s)
            #pragma unroll
            for (int hf = 0; hf < 2; ++hf) {
                const f32x4 gv = *(const f32x4*)&s_lng[32*s + 8*lg + 4*hf];  // broadcast reads
                const f32x4 bv = *(const f32x4*)&s_lnb[32*s + 8*lg + 4*hf];
                #pragma unroll
                for (int j = 0; j < 4; ++j) {
                    const float f = (xv[s][hf][j] - mu)*rstd*gv[j] + bv[j];
                    ax[s][4*hf + j] = (short)f2bf(f);
                }
            }

        // ---- down-proj MFMA + bias + exact GELU -> s_gl ----
        #pragma unroll
        for (int nt = 0; nt < 2; ++nt) {
            f32x4 acc = {0.f, 0.f, 0.f, 0.f};
            #pragma unroll
            for (int s = 0; s < 4; ++s)
                acc = __builtin_amdgcn_mfma_f32_16x16x32_bf16(ax[s], wd[s][nt], acc, 0, 0, 0);
            #pragma unroll
            for (int r = 0; r < 4; ++r) {
                const float vv = acc[r] + bdreg[nt];               // C/D: row=4*lg+r, col=lc
                const float ge = 0.5f*vv*(1.0f + erff(vv*0.70710678118654752f));
                s_gl[wave][(4*lg + r)*40 + 16*nt + lc] = f2bf(ge);
            }
        }
        __builtin_amdgcn_wave_barrier();

        // ---- up-proj: G (16x32) as A-frag, 8 N-tiles ----
        const short8 ag = *(const short8*)&s_gl[wave][lc*40 + 8*lg];
        #pragma unroll
        for (int nt = 0; nt < 8; ++nt) {
            f32x4 c2 = __builtin_amdgcn_mfma_f32_16x16x32_bf16(ag, wu[nt], (f32x4){0.f,0.f,0.f,0.f}, 0, 0, 0);
            if constexpr (MODE == 0) {
                #pragma unroll
                for (int r = 0; r < 4; ++r) {
                    const float hv = c2[r] + bupreg[nt];
                    sumacc[nt] += hv;
                    ssqacc[nt]  = fmaf(hv, hv, ssqacc[nt]);
                }
            } else {
                #pragma unroll
                for (int r = 0; r < 4; ++r) {
                    const size_t idx = (size_t)(tbase + 4*lg + r)*HD + h*ND + 16*nt + lc;
                    out[idx] = fmaf(areg[nt], c2[r], cfold[nt] + x[idx]);
                }
            }
        }
        __builtin_amdgcn_wave_barrier();   // before next tile overwrites s_gl
    }

    if constexpr (MODE == 0) {
        #pragma unroll
        for (int nt = 0; nt < 8; ++nt) {
            atomicAdd(&s_stats[0][16*nt + lc], sumacc[nt]);
            atomicAdd(&s_stats[1][16*nt + lc], ssqacc[nt]);
        }
        __syncthreads();
        if (tid < ND) {
            atomicAdd(gsum + h*ND + tid, s_stats[0][tid]);
            atomicAdd(gssq + h*ND + tid, s_stats[1][tid]);
        }
    }
}

// out = a*h + c + x with a = 0.1*g*rsqrt(var+eps), c = 0.1*beta - mean*a
__global__ void finalize_kernel(const float* __restrict__ gsum, const float* __restrict__ gssq,
                                const float* __restrict__ bn_g, const float* __restrict__ bn_b,
                                float* __restrict__ avec, float* __restrict__ cvec)
{
    const int i = blockIdx.x * blockDim.x + threadIdx.x;
    if (i < HD) {
        const float inv_n = 1.0f / (float)NT;
        const float mean = gsum[i] * inv_n;
        const float var  = gssq[i] * inv_n - mean*mean;
        const float rs   = rsqrtf(var + BN_EPS_F);
        const float a    = ADAPTER_SCALE * bn_g[i] * rs;
        avec[i] = a;
        cvec[i] = ADAPTER_SCALE * bn_b[i] - mean * a;
    }
}

extern "C" void kernel_launch(void* const* d_in, const int* in_sizes, int n_in,
                              void* d_out, int out_size, void* d_ws, size_t ws_size,
                              hipStream_t stream) {
    const float* x      = (const float*)d_in[0];
    const float* ln_g   = (const float*)d_in[1];
    const float* ln_b   = (const float*)d_in[2];
    const float* w_down = (const float*)d_in[3];
    const float* b_down = (const float*)d_in[4];
    const float* w_up   = (const float*)d_in[5];
    const float* b_up   = (const float*)d_in[6];
    const float* bn_g   = (const float*)d_in[7];
    const float* bn_b   = (const float*)d_in[8];
    float* out = (float*)d_out;

    float* ws   = (float*)d_ws;
    float* gsum = ws;            // [1024]
    float* gssq = ws + HD;       // [1024]
    float* avec = ws + 2*HD;     // [1024]
    float* cvec = ws + 3*HD;     // [1024]

    zero_kernel<<<(2*HD + 255)/256, 256, 0, stream>>>(gsum, 2*HD);
    adapter_mfma<0><<<NBLK, THREADS, 0, stream>>>(
        x, ln_g, ln_b, w_down, b_down, w_up, b_up,
        gsum, gssq, nullptr, nullptr, nullptr);
    finalize_kernel<<<(HD + 255)/256, 256, 0, stream>>>(gsum, gssq, bn_g, bn_b, avec, cvec);
    adapter_mfma<1><<<NBLK, THREADS, 0, stream>>>(
        x, ln_g, ln_b, w_down, b_down, w_up, b_up,
        nullptr, nullptr, avec, cvec, out);
}